// Round 3
// baseline (328.801 us; speedup 1.0000x reference)
//
#include <hip/hip_runtime.h>
#include <stdint.h>

typedef float f32x4 __attribute__((ext_vector_type(4)));
typedef __bf16 bf16x8 __attribute__((ext_vector_type(8)));
typedef unsigned short us8 __attribute__((ext_vector_type(8)));
typedef unsigned short us4 __attribute__((ext_vector_type(4)));
typedef unsigned int u32;

#define MFMA16(A, B, C) __builtin_amdgcn_mfma_f32_16x16x32_bf16( \
    __builtin_bit_cast(bf16x8, (A)), __builtin_bit_cast(bf16x8, (B)), (C), 0, 0, 0)

__device__ __forceinline__ unsigned short f2bf(float f) {
  u32 u = __builtin_bit_cast(u32, f);
  u = u + 0x7fffu + ((u >> 16) & 1u);   // RNE
  return (unsigned short)(u >> 16);
}
__device__ __forceinline__ float bf2f(unsigned short b) {
  u32 u = ((u32)b) << 16;
  return __builtin_bit_cast(float, u);
}
// async global->LDS, 16B per lane. LDS dest must be wave-uniform base (HW adds lane*16).
__device__ __forceinline__ void gload16(const void* g, void* lds) {
  __builtin_amdgcn_global_load_lds((const __attribute__((address_space(1))) u32*)g,
                                   (__attribute__((address_space(3))) u32*)lds, 16, 0, 0);
}

// ---------------- fp32 -> bf16 conversion of x and weights ----------------
__global__ __launch_bounds__(256) void convert_all(
    const float* __restrict__ x, const float* __restrict__ wq, const float* __restrict__ wk,
    const float* __restrict__ wv, const float* __restrict__ wo,
    unsigned short* __restrict__ xb, unsigned short* __restrict__ wcat,
    unsigned short* __restrict__ wob) {
  int tid = blockIdx.x * 256 + threadIdx.x;
  int nth = gridDim.x * 256;
  const float* srcs[5] = {x, wq, wk, wv, wo};
  unsigned short* dsts[5] = {xb, wcat, wcat + 4194304, wcat + 8388608, wob};
  const int n4s[5] = {2097152, 1048576, 1048576, 1048576, 1048576};
#pragma unroll
  for (int sg = 0; sg < 5; ++sg) {
    const float4* s = (const float4*)srcs[sg];
    us4* d = (us4*)dsts[sg];
    int n4 = n4s[sg];
    for (int i = tid; i < n4; i += nth) {
      float4 v = s[i];
      us4 o;
      o[0] = f2bf(v.x); o[1] = f2bf(v.y); o[2] = f2bf(v.z); o[3] = f2bf(v.w);
      d[i] = o;
    }
  }
}

// ---------------- 8-phase 256x256 bf16 GEMM, C = A * B^T (m201 template port) ----
// BM=BN=256, BK=64, 512 thr = 8 waves (2M x 4N), per-wave 128x64 = acc[2][2][4][2].
// LDS 128KB: 2 buffers x { A: 2 half-tiles 16KB, B: 2 half-tiles 16KB }.
// Half-tile layout is K-major subtiled: [kb 0..7][row 0..127][16B] so fragment
// reads are 256B-contiguous per 16-lane group (conflict-free); staging keeps the
// LDS dest linear and permutes the per-lane GLOBAL source instead (rule 21).
// 8 phases per iteration (2 K-tiles). vmcnt(2) checkpoints at ph3/ph7 only.
template <int EPI>
__global__ __launch_bounds__(512, 2) void gemm8(
    const unsigned short* __restrict__ A, const unsigned short* __restrict__ B,
    int nTN, int N,
    float* __restrict__ outF, const float* __restrict__ bias,
    unsigned short* __restrict__ qb, unsigned short* __restrict__ kb,
    unsigned short* __restrict__ vtb, const float* __restrict__ bq,
    const float* __restrict__ bv) {
  constexpr int KT = 32;  // K=2048 / BK=64
  __shared__ alignas(16) char L[131072];
  char* Lp = L;
  int bid = (int)blockIdx.x, nwg = (int)gridDim.x;
  {  // XCD-aware swizzle; grids are multiples of 8 (384, 128)
    int qq = nwg >> 3;
    int xcd = bid & 7, idx = bid >> 3;
    bid = xcd * qq + idx;
  }
  int tm = bid / nTN, tn = bid % nTN;
  int t = (int)threadIdx.x, l = t & 63, w = t >> 6;
  int g = l >> 4, ln = l & 15;
  int wr = w >> 2, wc = w & 3;   // 2M x 4N wave grid
  // staging source base: lane l covers global row (+l), k-block kb = w (8 elems)
  const unsigned short* pA = A + (size_t)(tm * 256 + l) * 2048 + w * 8;
  const unsigned short* pB = B + (size_t)(tn * 256 + l) * 2048 + w * 8;

  f32x4 acc[2][2][4][2] = {};
  us8 af[4][2], bf[2][2];

#define FENCE asm volatile("" ::: "memory")
#define BAR do { FENCE; __builtin_amdgcn_s_barrier(); FENCE; } while (0)
#define VMW_(n) asm volatile("s_waitcnt vmcnt(" #n ")" ::: "memory")
#define VMW(n) VMW_(n)
// stage one half-tile: op 0=A,1=B; half h; K-tile kt into buffer bufsel
#define HT(op, h, kt, bufsel) do { if ((kt) < KT) {                           \
    char* lb = Lp + (bufsel) * 65536 + (op) * 32768 + (h) * 16384 + w * 2048; \
    const unsigned short* gs = ((op) ? pB : pA) +                             \
        (size_t)((h) * 128) * 2048 + (size_t)(kt) * 64;                       \
    gload16(gs, lb);                                                          \
    gload16(gs + (size_t)64 * 2048, lb + 1024);                               \
  } } while (0)
#define RD_A(mh_, bufsel) do {                                                \
    _Pragma("unroll") for (int mf = 0; mf < 4; ++mf)                          \
    _Pragma("unroll") for (int kc = 0; kc < 2; ++kc)                          \
      af[mf][kc] = *(const us8*)(Lp + (bufsel) * 65536 + wr * 16384 +         \
          (kc * 4 + g) * 2048 + ((mh_) * 64 + mf * 16 + ln) * 16);            \
  } while (0)
#define RD_B(nh_, bufsel) do {                                                \
    _Pragma("unroll") for (int nf = 0; nf < 2; ++nf)                          \
    _Pragma("unroll") for (int kc = 0; kc < 2; ++kc)                          \
      bf[nf][kc] = *(const us8*)(Lp + (bufsel) * 65536 + 32768 +              \
          (wc >> 1) * 16384 + (kc * 4 + g) * 2048 +                           \
          ((wc & 1) * 64 + (nh_) * 32 + nf * 16 + ln) * 16);                  \
  } while (0)
#define MM(mh_, nh_) do {                                                     \
    __builtin_amdgcn_s_setprio(1);                                            \
    _Pragma("unroll") for (int mf = 0; mf < 4; ++mf)                          \
    _Pragma("unroll") for (int nf = 0; nf < 2; ++nf)                          \
    _Pragma("unroll") for (int kc = 0; kc < 2; ++kc)                          \
      acc[mh_][nh_][mf][nf] = MFMA16(af[mf][kc], bf[nf][kc],                  \
                                     acc[mh_][nh_][mf][nf]);                  \
    __builtin_amdgcn_s_setprio(0);                                            \
  } while (0)
// one iteration = K-tiles k0 (buf0) and k0+1 (buf1); stages k0+2 / k0+3.
// Region-reuse ledger: A(buf) last read at its ph2-slot, B at ph3-slot; every
// HT below lands >= 1 barrier after the last read of the region it overwrites.
#define ITER(k0, VM3) do { int k1_ = (k0) + 1;                                \
  /*ph0*/ RD_A(0, 0); RD_B(0, 0); HT(0, 1, k1_, 1);     BAR; MM(0, 0); BAR;   \
  /*ph1*/ RD_B(1, 0);             HT(1, 0, k1_, 1);     BAR; MM(0, 1); BAR;   \
  /*ph2*/ RD_A(1, 0);             HT(1, 1, k1_, 1);     BAR; MM(1, 1); BAR;   \
  /*ph3*/ RD_B(0, 0);             HT(0, 0, (k0) + 2, 0); BAR; MM(1, 0);       \
          VMW(VM3); BAR;                                                      \
  /*ph4*/ RD_A(0, 1); RD_B(0, 1); HT(0, 1, (k0) + 2, 0); BAR; MM(0, 0); BAR;  \
  /*ph5*/ RD_B(1, 1);             HT(1, 0, (k0) + 2, 0); BAR; MM(0, 1); BAR;  \
  /*ph6*/ RD_A(1, 1);             HT(1, 1, (k0) + 2, 0); BAR; MM(1, 1); BAR;  \
  /*ph7*/ RD_B(0, 1);             HT(0, 0, k1_ + 2, 1);  BAR; MM(1, 0);       \
          VMW(2); BAR;                                                        \
} while (0)

  // prologue: tile0 fully + Ah0(tile1); then all-but-last-half-tile landed
  HT(0, 0, 0, 0); HT(0, 1, 0, 0); HT(1, 0, 0, 0); HT(1, 1, 0, 0);
  HT(0, 0, 1, 1);
  VMW(2); BAR;

#pragma unroll 1
  for (int it = 0; it < 15; ++it) ITER(2 * it, 2);
  ITER(30, 0);  // peeled tail: stages for tiles 32/33 skipped by HT guard

#undef ITER
#undef MM
#undef RD_B
#undef RD_A
#undef HT
#undef VMW
#undef VMW_
#undef BAR
#undef FENCE

  if (EPI == 1) {
#pragma unroll
    for (int mh = 0; mh < 2; ++mh)
#pragma unroll
    for (int nh = 0; nh < 2; ++nh)
#pragma unroll
    for (int mf = 0; mf < 4; ++mf)
#pragma unroll
    for (int nf = 0; nf < 2; ++nf) {
      int n = tn * 256 + wc * 64 + nh * 32 + nf * 16 + ln;
      float bz = bias[n];
      int m0 = tm * 256 + wr * 128 + mh * 64 + mf * 16 + g * 4;
#pragma unroll
      for (int r = 0; r < 4; ++r)
        outF[(size_t)(m0 + r) * N + n] = acc[mh][nh][mf][nf][r] + bz;
    }
  } else {
#pragma unroll
    for (int mh = 0; mh < 2; ++mh)
#pragma unroll
    for (int nh = 0; nh < 2; ++nh)
#pragma unroll
    for (int mf = 0; mf < 4; ++mf)
#pragma unroll
    for (int nf = 0; nf < 2; ++nf) {
      int n6 = tn * 256 + wc * 64 + nh * 32 + nf * 16 + ln;
      int sel = n6 >> 11, d = n6 & 2047, h = d >> 7, hd = d & 127;
      int m0 = tm * 256 + wr * 128 + mh * 64 + mf * 16 + g * 4;
      int b = m0 >> 11, s0 = m0 & 2047;
      if (sel == 2) {  // v -> transposed [bh][hd][S]
        float badd = bv[d];
        us4 pk;
#pragma unroll
        for (int r = 0; r < 4; ++r) pk[r] = f2bf(acc[mh][nh][mf][nf][r] + badd);
        *(us4*)&vtb[((size_t)(b * 16 + h) * 128 + hd) * 2048 + s0] = pk;
      } else {  // q/k -> [bh][S][hd]
        unsigned short* dst = sel ? kb : qb;
        float badd = sel ? 0.f : bq[d];
#pragma unroll
        for (int r = 0; r < 4; ++r)
          dst[((size_t)(b * 16 + h) * 2048 + (s0 + r)) * 128 + hd] =
              f2bf(acc[mh][nh][mf][nf][r] + badd);
      }
    }
  }
}

// ---------------- interleaved RoPE on q,k in place ----------------
__global__ __launch_bounds__(256) void rope_k(u32* __restrict__ q, u32* __restrict__ k) {
  int idx = blockIdx.x * 256 + threadIdx.x;  // exactly 2*16*2048*64
  int i = idx & 63;
  int s = (idx >> 6) & 2047;
  float ang = (float)s * exp2f(-(float)i * 0.2076205059304703f);
  float sv, cv;
  sincosf(ang, &sv, &cv);
  u32 qu = q[idx];
  float a0 = bf2f((unsigned short)(qu & 0xffff)), a1 = bf2f((unsigned short)(qu >> 16));
  q[idx] = (u32)f2bf(a0 * cv - a1 * sv) | ((u32)f2bf(a1 * cv + a0 * sv) << 16);
  u32 ku = k[idx];
  float b0 = bf2f((unsigned short)(ku & 0xffff)), b1 = bf2f((unsigned short)(ku >> 16));
  k[idx] = (u32)f2bf(b0 * cv - b1 * sv) | ((u32)f2bf(b1 * cv + b0 * sv) << 16);
}

// ---------------- causal flash attention ----------------
__global__ __launch_bounds__(512) void attn_k(
    const unsigned short* __restrict__ qg, const unsigned short* __restrict__ kg,
    const unsigned short* __restrict__ vtg, unsigned short* __restrict__ ab) {
  __shared__ alignas(16) unsigned short Kl[64 * 128];   // [key][hd], swizzled
  __shared__ alignas(16) unsigned short Vl[128 * 64];   // [hd][key], swizzled
  __shared__ alignas(16) unsigned short Pl[8][16 * 72]; // per wave [qrow][key+pad]
  int bh = (int)blockIdx.x & 31;
  int pr = (int)blockIdx.x >> 5;
  int t = (int)threadIdx.x, l = t & 63, w = t >> 6;
  int g = l >> 4, ln = l & 15;
  int b = bh >> 4, h = bh & 15;
  const size_t bq0 = (size_t)bh * 2048 * 128;

#pragma unroll 1
  for (int half = 0; half < 2; ++half) {
    int qt = half ? 15 - pr : pr;
    int qbase = qt * 128;
    int qrow = qbase + w * 16 + ln;
    us8 qf[4];
#pragma unroll
    for (int kf = 0; kf < 4; ++kf)
      qf[kf] = *(const us8*)&qg[bq0 + (size_t)qrow * 128 + kf * 32 + g * 8];
    f32x4 o[8] = {};
    float mrow = -1e30f, lrow = 0.f;
    int nkt = (qbase >> 6) + 2;
#pragma unroll 1
    for (int kt = 0; kt < nkt; ++kt) {
      __syncthreads();
#pragma unroll
      for (int i = 0; i < 2; ++i) {
        int fb = i * 8192 + w * 1024;
        int flat = fb + l * 16;
        int row = flat >> 8, colb = flat & 255;
        int sc = colb ^ ((row & 7) << 4);  // pre-swizzled global source (m173)
        gload16(kg + (bq0 + (size_t)(kt * 64 + row) * 128 + (sc >> 1)), (char*)Kl + fb);
        int rv = flat >> 7, cv2 = flat & 127;
        int scv = cv2 ^ ((rv & 7) << 4);
        gload16(vtg + (bq0 + (size_t)rv * 2048 + kt * 64 + (scv >> 1)), (char*)Vl + fb);
      }
      __syncthreads();
      // S^T = K * Q^T : D[key_local][qrow_local]
      f32x4 st[4];
#pragma unroll
      for (int kfr = 0; kfr < 4; ++kfr) {
        f32x4 acc = {};
        int row = kfr * 16 + ln;
        int swz = (row & 7) << 4;
#pragma unroll
        for (int kf = 0; kf < 4; ++kf) {
          us8 kfrag = *(const us8*)((const char*)Kl + row * 256 + ((kf * 64 + g * 16) ^ swz));
          acc = MFMA16(kfrag, qf[kf], acc);
        }
        st[kfr] = acc;
      }
      float pmax = -1e30f;
#pragma unroll
      for (int kfr = 0; kfr < 4; ++kfr)
#pragma unroll
        for (int r = 0; r < 4; ++r) {
          int key = kt * 64 + kfr * 16 + g * 4 + r;
          float sv = key <= qrow ? st[kfr][r] * 0.08838834764831845f : -1e30f;
          st[kfr][r] = sv;
          pmax = fmaxf(pmax, sv);
        }
      pmax = fmaxf(pmax, __shfl_xor(pmax, 16));
      pmax = fmaxf(pmax, __shfl_xor(pmax, 32));
      if (__ballot(pmax > mrow + 8.f)) {
        float mnew = pmax > mrow + 8.f ? pmax : mrow;
        float corr = exp2f((mrow - mnew) * 1.44269504f);
        mrow = mnew;
        lrow *= corr;
#pragma unroll
        for (int r = 0; r < 4; ++r) {
          float cr = __shfl(corr, g * 4 + r);
#pragma unroll
          for (int nf = 0; nf < 8; ++nf) o[nf][r] *= cr;
        }
      }
      float lsum = 0.f;
#pragma unroll
      for (int kfr = 0; kfr < 4; ++kfr) {
        us4 pk;
#pragma unroll
        for (int r = 0; r < 4; ++r) {
          float p = exp2f((st[kfr][r] - mrow) * 1.44269504f);
          lsum += p;
          pk[r] = f2bf(p);
        }
        *(us4*)&Pl[w][ln * 72 + kfr * 16 + g * 4] = pk;
      }
      lsum += __shfl_xor(lsum, 16);
      lsum += __shfl_xor(lsum, 32);
      lrow += lsum;
#pragma unroll
      for (int kf2 = 0; kf2 < 2; ++kf2) {
        us8 pa = *(const us8*)&Pl[w][ln * 72 + kf2 * 32 + g * 8];
#pragma unroll
        for (int nf = 0; nf < 8; ++nf) {
          int row = nf * 16 + ln;
          us8 vb = *(const us8*)((const char*)Vl + row * 128 +
                                 ((kf2 * 64 + g * 16) ^ ((row & 7) << 4)));
          o[nf] = MFMA16(pa, vb, o[nf]);
        }
      }
    }  // kt
    float invl = 1.f / lrow;
#pragma unroll
    for (int r = 0; r < 4; ++r) {
      float ir = __shfl(invl, g * 4 + r);
      int srow = qbase + w * 16 + g * 4 + r;
      size_t base = ((size_t)b * 2048 + srow) * 2048 + h * 128 + ln;
#pragma unroll
      for (int nf = 0; nf < 8; ++nf) ab[base + (size_t)nf * 16] = f2bf(o[nf][r] * ir);
    }
  }  // half
}

extern "C" void kernel_launch(void* const* d_in, const int* in_sizes, int n_in,
                              void* d_out, int out_size, void* d_ws, size_t ws_size,
                              hipStream_t stream) {
  const float* x  = (const float*)d_in[0];
  const float* Wq = (const float*)d_in[1];
  const float* bq = (const float*)d_in[2];
  const float* Wk = (const float*)d_in[3];
  const float* Wv = (const float*)d_in[4];
  const float* bv = (const float*)d_in[5];
  const float* Wo = (const float*)d_in[6];
  const float* bo = (const float*)d_in[7];
  float* out = (float*)d_out;

  unsigned short* ws = (unsigned short*)d_ws;
  unsigned short* xb   = ws;                // 8388608 elems (x bf16; later reused as attn out)
  unsigned short* wcat = xb + 8388608;      // 12582912 (Wq|Wk|Wv rows, [6144][2048])
  unsigned short* wob  = wcat + 12582912;   // 4194304
  unsigned short* qb   = wob + 4194304;     // 8388608  [32][2048][128]
  unsigned short* kb   = qb + 8388608;      // 8388608
  unsigned short* vtb  = kb + 8388608;      // 8388608  [32][128][2048] (transposed)

  convert_all<<<2048, 256, 0, stream>>>(x, Wq, Wk, Wv, Wo, xb, wcat, wob);
  gemm8<0><<<384, 512, 0, stream>>>(xb, wcat, 24, 6144,
                                    nullptr, nullptr, qb, kb, vtb, bq, bv);
  rope_k<<<16384, 256, 0, stream>>>((u32*)qb, (u32*)kb);
  attn_k<<<256, 512, 0, stream>>>(qb, kb, vtb, xb /* a_buf alias */);
  gemm8<1><<<128, 512, 0, stream>>>(xb, wob, 8, 2048,
                                    out, bo, nullptr, nullptr, nullptr, nullptr, nullptr);
}

// Round 5
// 299.800 us; speedup vs baseline: 1.0967x; 1.0967x over previous
//
#include <hip/hip_runtime.h>
#include <stdint.h>

typedef float f32x4 __attribute__((ext_vector_type(4)));
typedef __bf16 bf16x8 __attribute__((ext_vector_type(8)));
typedef unsigned short us8 __attribute__((ext_vector_type(8)));
typedef unsigned short us4 __attribute__((ext_vector_type(4)));
typedef unsigned int u32;

#define MFMA16(A, B, C) __builtin_amdgcn_mfma_f32_16x16x32_bf16( \
    __builtin_bit_cast(bf16x8, (A)), __builtin_bit_cast(bf16x8, (B)), (C), 0, 0, 0)

__device__ __forceinline__ unsigned short f2bf(float f) {
  u32 u = __builtin_bit_cast(u32, f);
  u = u + 0x7fffu + ((u >> 16) & 1u);   // RNE
  return (unsigned short)(u >> 16);
}
__device__ __forceinline__ float bf2f(unsigned short b) {
  u32 u = ((u32)b) << 16;
  return __builtin_bit_cast(float, u);
}
// async global->LDS, 16B per lane. LDS dest must be wave-uniform base (HW adds lane*16).
__device__ __forceinline__ void gload16(const void* g, void* lds) {
  __builtin_amdgcn_global_load_lds((const __attribute__((address_space(1))) u32*)g,
                                   (__attribute__((address_space(3))) u32*)lds, 16, 0, 0);
}

// ---------------- fp32 -> bf16 conversion of x and weights ----------------
__global__ __launch_bounds__(256) void convert_all(
    const float* __restrict__ x, const float* __restrict__ wq, const float* __restrict__ wk,
    const float* __restrict__ wv, const float* __restrict__ wo,
    unsigned short* __restrict__ xb, unsigned short* __restrict__ wcat,
    unsigned short* __restrict__ wob) {
  int tid = blockIdx.x * 256 + threadIdx.x;
  int nth = gridDim.x * 256;
  const float* srcs[5] = {x, wq, wk, wv, wo};
  unsigned short* dsts[5] = {xb, wcat, wcat + 4194304, wcat + 8388608, wob};
  const int n4s[5] = {2097152, 1048576, 1048576, 1048576, 1048576};
#pragma unroll
  for (int sg = 0; sg < 5; ++sg) {
    const float4* s = (const float4*)srcs[sg];
    us4* d = (us4*)dsts[sg];
    int n4 = n4s[sg];
    for (int i = tid; i < n4; i += nth) {
      float4 v = s[i];
      us4 o;
      o[0] = f2bf(v.x); o[1] = f2bf(v.y); o[2] = f2bf(v.z); o[3] = f2bf(v.w);
      d[i] = o;
    }
  }
}

// ---------------- 8-phase 256x256 bf16 GEMM, C = A * B^T (m201 template) -------
// BM=BN=256, BK=64, 512 thr = 8 waves (2M x 4N), per-wave 128x64 = acc[2][2][4][2].
// LDS 128KB: 2 buffers x { A-h0, A-h1, B-h0, B-h1 } 16KB regions, K-major subtiled
// [kb][row][16B] -> conflict-free ds_read_b128 (R3: BANK_CONFLICT=0).
// R5 SCHEDULE (race-free, re-derived from per-wave region reads):
//   Reads per tile t (buf b): ph0 = RD_A(0)+RD_B(0)+RD_B(1)  [B fully in regs],
//   ph2 = RD_A(1). Region last-read: B-h0 ph0, B-h1 ph1(use), A-h* ph2.
//   Quadrant order: MM(0,0) ph0, MM(0,1) ph1, MM(1,0) ph2, MM(1,1) ph3.
//   Stages (1 HT/phase): ph0 -> A-h1(t+1, other buf)   [other buf A last read t-1.ph2]
//                        ph1 -> B-h0(t+2, b)           [b.B-h0 last read t.ph0]
//                        ph2 -> B-h1(t+2, b)           [b.B-h1 consumed t.ph1]
//                        ph3 -> A-h0(t+2, b)           [b.A-h0 last read t.ph2]
//   Boundary VMW(6) (once per tile, end of ph3): confirms A-h1(t+1) (issued t.ph0,
//   ~3 phases cover) + everything older; leaves 3 HTs (t+2's B0,B1,A0) in flight.
template <int EPI>
__global__ __launch_bounds__(512, 2) void gemm8(
    const unsigned short* __restrict__ A, const unsigned short* __restrict__ B,
    int nTN, int N,
    float* __restrict__ outF, const float* __restrict__ bias,
    unsigned short* __restrict__ qb, unsigned short* __restrict__ kb,
    unsigned short* __restrict__ vtb, const float* __restrict__ bq,
    const float* __restrict__ bv) {
  constexpr int KT = 32;  // K=2048 / BK=64
  __shared__ alignas(16) char L[131072];
  char* Lp = L;
  int bid = (int)blockIdx.x, nwg = (int)gridDim.x;
  {  // XCD-aware swizzle; grids are multiples of 8
    int qq = nwg >> 3;
    int xcd = bid & 7, idx = bid >> 3;
    bid = xcd * qq + idx;
  }
  int tm = bid / nTN, tn = bid % nTN;
  int t = (int)threadIdx.x, l = t & 63, w = t >> 6;
  int g = l >> 4, ln = l & 15;
  int wr = w >> 2, wc = w & 3;   // 2M x 4N wave grid
  // staging source base: lane l covers global row (+l), k-chunk = w (8 elems)
  const unsigned short* pA = A + (size_t)(tm * 256 + l) * 2048 + w * 8;
  const unsigned short* pB = B + (size_t)(tn * 256 + l) * 2048 + w * 8;

  f32x4 acc[2][2][4][2] = {};
  us8 af[4][2], bf[2][2][2];

#define FENCE asm volatile("" ::: "memory")
#define BAR do { FENCE; __builtin_amdgcn_s_barrier(); FENCE; } while (0)
#define VMW_(n) asm volatile("s_waitcnt vmcnt(" #n ")" ::: "memory")
#define VMW(n) VMW_(n)
// stage one half-tile: op 0=A,1=B; half h; K-tile kt into buffer bufsel
#define HT(op, h, kt, bufsel) do { if ((kt) < KT) {                           \
    char* lb = Lp + (bufsel) * 65536 + (op) * 32768 + (h) * 16384 + w * 2048; \
    const unsigned short* gs = ((op) ? pB : pA) +                             \
        (size_t)((h) * 128) * 2048 + (size_t)(kt) * 64;                       \
    gload16(gs, lb);                                                          \
    gload16(gs + (size_t)64 * 2048, lb + 1024);                               \
  } } while (0)
#define RD_A(mh_, bufsel) do {                                                \
    _Pragma("unroll") for (int mf = 0; mf < 4; ++mf)                          \
    _Pragma("unroll") for (int kc = 0; kc < 2; ++kc)                          \
      af[mf][kc] = *(const us8*)(Lp + (bufsel) * 65536 + wr * 16384 +         \
          (kc * 4 + g) * 2048 + ((mh_) * 64 + mf * 16 + ln) * 16);            \
  } while (0)
#define RD_B(nh_, bufsel) do {                                                \
    _Pragma("unroll") for (int nf = 0; nf < 2; ++nf)                          \
    _Pragma("unroll") for (int kc = 0; kc < 2; ++kc)                          \
      bf[nh_][nf][kc] = *(const us8*)(Lp + (bufsel) * 65536 + 32768 +         \
          (wc >> 1) * 16384 + (kc * 4 + g) * 2048 +                           \
          ((wc & 1) * 64 + (nh_) * 32 + nf * 16 + ln) * 16);                  \
  } while (0)
#define MM(mh_, nh_) do {                                                     \
    __builtin_amdgcn_s_setprio(1);                                            \
    _Pragma("unroll") for (int mf = 0; mf < 4; ++mf)                          \
    _Pragma("unroll") for (int nf = 0; nf < 2; ++nf)                          \
    _Pragma("unroll") for (int kc = 0; kc < 2; ++kc)                          \
      acc[mh_][nh_][mf][nf] = MFMA16(af[mf][kc], bf[nh_][nf][kc],             \
                                     acc[mh_][nh_][mf][nf]);                  \
    __builtin_amdgcn_s_setprio(0);                                            \
  } while (0)
// One tile = 4 phases. b = kt&1 (literal), ob = b^1.
#define TILE(kt, b, VM) do {                                                  \
  /*ph0*/ RD_A(0, b); RD_B(0, b); RD_B(1, b);                                 \
          HT(0, 1, (kt) + 1, (b) ^ 1);                                        \
          BAR; MM(0, 0); BAR;                                                 \
  /*ph1*/ HT(1, 0, (kt) + 2, b);                                              \
          BAR; MM(0, 1); BAR;                                                 \
  /*ph2*/ RD_A(1, b);                                                         \
          HT(1, 1, (kt) + 2, b);                                              \
          BAR; MM(1, 0); BAR;                                                 \
  /*ph3*/ HT(0, 0, (kt) + 2, b);                                              \
          MM(1, 1); VMW(VM); BAR;                                             \
} while (0)

  // prologue: issue order = tile0 {A-h0, B-h0, B-h1}, then A-h1(0) and tile1's
  // {B-h0, B-h1, A-h0} (mimicking steady-state t-1.ph0..ph3 stage order).
  // VMW(6) confirms all 4 HTs of tile 0; leaves tile1's 3 HTs in flight.
  HT(0, 0, 0, 0); HT(1, 0, 0, 0); HT(1, 1, 0, 0);
  HT(0, 1, 0, 0); HT(1, 0, 1, 1); HT(1, 1, 1, 1); HT(0, 0, 1, 1);
  VMW(6); BAR;

#pragma unroll 1
  for (int it = 0; it < 15; ++it) {
    TILE(2 * it, 0, 6);
    TILE(2 * it + 1, 1, 6);
  }
  TILE(30, 0, 0);  // drains A-h1(31) (+ tile31's already-issued B0,B1,A0)
  TILE(31, 1, 0);  // all stages guarded out; VMW(0) no-op

#undef TILE
#undef MM
#undef RD_B
#undef RD_A
#undef HT
#undef VMW
#undef VMW_
#undef BAR
#undef FENCE

  if (EPI == 1) {
#pragma unroll
    for (int mh = 0; mh < 2; ++mh)
#pragma unroll
    for (int nh = 0; nh < 2; ++nh)
#pragma unroll
    for (int mf = 0; mf < 4; ++mf)
#pragma unroll
    for (int nf = 0; nf < 2; ++nf) {
      int n = tn * 256 + wc * 64 + nh * 32 + nf * 16 + ln;
      float bz = bias[n];
      int m0 = tm * 256 + wr * 128 + mh * 64 + mf * 16 + g * 4;
#pragma unroll
      for (int r = 0; r < 4; ++r)
        outF[(size_t)(m0 + r) * N + n] = acc[mh][nh][mf][nf][r] + bz;
    }
  } else {
#pragma unroll
    for (int mh = 0; mh < 2; ++mh)
#pragma unroll
    for (int nh = 0; nh < 2; ++nh)
#pragma unroll
    for (int mf = 0; mf < 4; ++mf)
#pragma unroll
    for (int nf = 0; nf < 2; ++nf) {
      int n6 = tn * 256 + wc * 64 + nh * 32 + nf * 16 + ln;
      int sel = n6 >> 11, d = n6 & 2047, h = d >> 7, hd = d & 127;
      int m0 = tm * 256 + wr * 128 + mh * 64 + mf * 16 + g * 4;
      int b = m0 >> 11, s0 = m0 & 2047;
      if (sel == 2) {  // v -> transposed [bh][hd][S]
        float badd = bv[d];
        us4 pk;
#pragma unroll
        for (int r = 0; r < 4; ++r) pk[r] = f2bf(acc[mh][nh][mf][nf][r] + badd);
        *(us4*)&vtb[((size_t)(b * 16 + h) * 128 + hd) * 2048 + s0] = pk;
      } else {  // q/k -> [bh][S][hd]
        unsigned short* dst = sel ? kb : qb;
        float badd = sel ? 0.f : bq[d];
#pragma unroll
        for (int r = 0; r < 4; ++r)
          dst[((size_t)(b * 16 + h) * 2048 + (s0 + r)) * 128 + hd] =
              f2bf(acc[mh][nh][mf][nf][r] + badd);
      }
    }
  }
}

// ---------------- R2-verified 128x256 deep-prefetch GEMM (out-proj) ----------
// BM=128, BN=256, BK=32; 512 thr = 8 waves; 4 LDS tile-buffers (24KB each),
// staged 3 tiles ahead; vmcnt(6) steady state. Verified passing in R2.
template <int EPI>
__global__ __launch_bounds__(512, 2) void gemm2(
    const unsigned short* __restrict__ A, const unsigned short* __restrict__ B,
    int nTN, int N,
    float* __restrict__ outF, const float* __restrict__ bias) {
  constexpr int K = 2048, KT = 64;
  __shared__ alignas(16) char L[4 * 24576];
  int bid = (int)blockIdx.x, nwg = (int)gridDim.x;
  {
    int qq = nwg >> 3;
    int xcd = bid & 7, idx = bid >> 3;
    bid = xcd * qq + idx;
  }
  int tm = bid / nTN, tn = bid % nTN;
  int t = (int)threadIdx.x, l = t & 63, w = t >> 6;
  int g = l >> 4, ln = l & 15;
  int wr = w >> 2, wc = w & 3;
  const unsigned short* Ab =
      A + (size_t)(tm * 128 + w * 16 + (l >> 2)) * K + (l & 3) * 8;
  const unsigned short* Bb =
      B + (size_t)(tn * 256 + w * 16 + (l >> 2)) * K + (l & 3) * 8;
  f32x4 acc[4][4] = {};

#define STAGE(tile) do {                                                      \
    char* Lb = L + ((tile) & 3) * 24576 + w * 1024;                           \
    int kc = (tile) * 32;                                                     \
    gload16(Ab + kc, Lb);                                                     \
    gload16(Bb + kc, Lb + 8192);                                              \
    gload16(Bb + (size_t)128 * K + kc, Lb + 16384);                           \
  } while (0)

#define GITER(kt, VM) do {                                                    \
    asm volatile("s_waitcnt vmcnt(" #VM ")" ::: "memory");                    \
    __builtin_amdgcn_s_barrier();                                             \
    __builtin_amdgcn_sched_barrier(0);                                        \
    asm volatile("" ::: "memory");                                            \
    if ((kt) + 3 < KT) STAGE((kt) + 3);                                       \
    const unsigned short* Lc = (const unsigned short*)(L + ((kt) & 3) * 24576); \
    us8 af[4], bfr[4];                                                        \
    _Pragma("unroll") for (int mf = 0; mf < 4; ++mf)                          \
      af[mf] = *(const us8*)&Lc[(wr * 64 + mf * 16 + ln) * 32 + g * 8];       \
    _Pragma("unroll") for (int nf = 0; nf < 4; ++nf)                          \
      bfr[nf] = *(const us8*)&Lc[4096 + (wc * 64 + nf * 16 + ln) * 32 + g * 8]; \
    __builtin_amdgcn_s_setprio(1);                                            \
    _Pragma("unroll") for (int mf = 0; mf < 4; ++mf)                          \
      _Pragma("unroll") for (int nf = 0; nf < 4; ++nf)                        \
        acc[mf][nf] = MFMA16(af[mf], bfr[nf], acc[mf][nf]);                   \
    __builtin_amdgcn_s_setprio(0);                                            \
  } while (0)

  STAGE(0); STAGE(1); STAGE(2);
#pragma unroll 1
  for (int kt = 0; kt < KT - 2; ++kt) GITER(kt, 6);
  GITER(KT - 2, 3);
  GITER(KT - 1, 0);
#undef STAGE
#undef GITER

#pragma unroll
  for (int mf = 0; mf < 4; ++mf)
#pragma unroll
    for (int nf = 0; nf < 4; ++nf) {
      int n = tn * 256 + wc * 64 + nf * 16 + ln;
      float bz = bias[n];
#pragma unroll
      for (int r = 0; r < 4; ++r) {
        int m = tm * 128 + wr * 64 + mf * 16 + g * 4 + r;
        outF[(size_t)m * N + n] = acc[mf][nf][r] + bz;
      }
    }
}

// ---------------- interleaved RoPE on q,k in place ----------------
__global__ __launch_bounds__(256) void rope_k(u32* __restrict__ q, u32* __restrict__ k) {
  int idx = blockIdx.x * 256 + threadIdx.x;  // exactly 2*16*2048*64
  int i = idx & 63;
  int s = (idx >> 6) & 2047;
  float ang = (float)s * exp2f(-(float)i * 0.2076205059304703f);
  float sv, cv;
  sincosf(ang, &sv, &cv);
  u32 qu = q[idx];
  float a0 = bf2f((unsigned short)(qu & 0xffff)), a1 = bf2f((unsigned short)(qu >> 16));
  q[idx] = (u32)f2bf(a0 * cv - a1 * sv) | ((u32)f2bf(a1 * cv + a0 * sv) << 16);
  u32 ku = k[idx];
  float b0 = bf2f((unsigned short)(ku & 0xffff)), b1 = bf2f((unsigned short)(ku >> 16));
  k[idx] = (u32)f2bf(b0 * cv - b1 * sv) | ((u32)f2bf(b1 * cv + b0 * sv) << 16);
}

// ---------------- causal flash attention ----------------
__global__ __launch_bounds__(512) void attn_k(
    const unsigned short* __restrict__ qg, const unsigned short* __restrict__ kg,
    const unsigned short* __restrict__ vtg, unsigned short* __restrict__ ab) {
  __shared__ alignas(16) unsigned short Kl[64 * 128];   // [key][hd], swizzled
  __shared__ alignas(16) unsigned short Vl[128 * 64];   // [hd][key], swizzled
  __shared__ alignas(16) unsigned short Pl[8][16 * 72]; // per wave [qrow][key+pad]
  int bh = (int)blockIdx.x & 31;
  int pr = (int)blockIdx.x >> 5;
  int t = (int)threadIdx.x, l = t & 63, w = t >> 6;
  int g = l >> 4, ln = l & 15;
  int b = bh >> 4, h = bh & 15;
  const size_t bq0 = (size_t)bh * 2048 * 128;

#pragma unroll 1
  for (int half = 0; half < 2; ++half) {
    int qt = half ? 15 - pr : pr;
    int qbase = qt * 128;
    int qrow = qbase + w * 16 + ln;
    us8 qf[4];
#pragma unroll
    for (int kf = 0; kf < 4; ++kf)
      qf[kf] = *(const us8*)&qg[bq0 + (size_t)qrow * 128 + kf * 32 + g * 8];
    f32x4 o[8] = {};
    float mrow = -1e30f, lrow = 0.f;
    int nkt = (qbase >> 6) + 2;
#pragma unroll 1
    for (int kt = 0; kt < nkt; ++kt) {
      __syncthreads();
#pragma unroll
      for (int i = 0; i < 2; ++i) {
        int fb = i * 8192 + w * 1024;
        int flat = fb + l * 16;
        int row = flat >> 8, colb = flat & 255;
        int sc = colb ^ ((row & 7) << 4);  // pre-swizzled global source (m173)
        gload16(kg + (bq0 + (size_t)(kt * 64 + row) * 128 + (sc >> 1)), (char*)Kl + fb);
        int rv = flat >> 7, cv2 = flat & 127;
        int scv = cv2 ^ ((rv & 7) << 4);
        gload16(vtg + (bq0 + (size_t)rv * 2048 + kt * 64 + (scv >> 1)), (char*)Vl + fb);
      }
      __syncthreads();
      // S^T = K * Q^T : D[key_local][qrow_local]
      f32x4 st[4];
#pragma unroll
      for (int kfr = 0; kfr < 4; ++kfr) {
        f32x4 acc = {};
        int row = kfr * 16 + ln;
        int swz = (row & 7) << 4;
#pragma unroll
        for (int kf = 0; kf < 4; ++kf) {
          us8 kfrag = *(const us8*)((const char*)Kl + row * 256 + ((kf * 64 + g * 16) ^ swz));
          acc = MFMA16(kfrag, qf[kf], acc);
        }
        st[kfr] = acc;
      }
      float pmax = -1e30f;
#pragma unroll
      for (int kfr = 0; kfr < 4; ++kfr)
#pragma unroll
        for (int r = 0; r < 4; ++r) {
          int key = kt * 64 + kfr * 16 + g * 4 + r;
          float sv = key <= qrow ? st[kfr][r] * 0.08838834764831845f : -1e30f;
          st[kfr][r] = sv;
          pmax = fmaxf(pmax, sv);
        }
      pmax = fmaxf(pmax, __shfl_xor(pmax, 16));
      pmax = fmaxf(pmax, __shfl_xor(pmax, 32));
      if (__ballot(pmax > mrow + 8.f)) {
        float mnew = pmax > mrow + 8.f ? pmax : mrow;
        float corr = exp2f((mrow - mnew) * 1.44269504f);
        mrow = mnew;
        lrow *= corr;
#pragma unroll
        for (int r = 0; r < 4; ++r) {
          float cr = __shfl(corr, g * 4 + r);
#pragma unroll
          for (int nf = 0; nf < 8; ++nf) o[nf][r] *= cr;
        }
      }
      float lsum = 0.f;
#pragma unroll
      for (int kfr = 0; kfr < 4; ++kfr) {
        us4 pk;
#pragma unroll
        for (int r = 0; r < 4; ++r) {
          float p = exp2f((st[kfr][r] - mrow) * 1.44269504f);
          lsum += p;
          pk[r] = f2bf(p);
        }
        *(us4*)&Pl[w][ln * 72 + kfr * 16 + g * 4] = pk;
      }
      lsum += __shfl_xor(lsum, 16);
      lsum += __shfl_xor(lsum, 32);
      lrow += lsum;
#pragma unroll
      for (int kf2 = 0; kf2 < 2; ++kf2) {
        us8 pa = *(const us8*)&Pl[w][ln * 72 + kf2 * 32 + g * 8];
#pragma unroll
        for (int nf = 0; nf < 8; ++nf) {
          int row = nf * 16 + ln;
          us8 vb = *(const us8*)((const char*)Vl + row * 128 +
                                 ((kf2 * 64 + g * 16) ^ ((row & 7) << 4)));
          o[nf] = MFMA16(pa, vb, o[nf]);
        }
      }
    }  // kt
    float invl = 1.f / lrow;
#pragma unroll
    for (int r = 0; r < 4; ++r) {
      float ir = __shfl(invl, g * 4 + r);
      int srow = qbase + w * 16 + g * 4 + r;
      size_t base = ((size_t)b * 2048 + srow) * 2048 + h * 128 + ln;
#pragma unroll
      for (int nf = 0; nf < 8; ++nf) ab[base + (size_t)nf * 16] = f2bf(o[nf][r] * ir);
    }
  }  // half
}

extern "C" void kernel_launch(void* const* d_in, const int* in_sizes, int n_in,
                              void* d_out, int out_size, void* d_ws, size_t ws_size,
                              hipStream_t stream) {
  const float* x  = (const float*)d_in[0];
  const float* Wq = (const float*)d_in[1];
  const float* bq = (const float*)d_in[2];
  const float* Wk = (const float*)d_in[3];
  const float* Wv = (const float*)d_in[4];
  const float* bv = (const float*)d_in[5];
  const float* Wo = (const float*)d_in[6];
  const float* bo = (const float*)d_in[7];
  float* out = (float*)d_out;

  unsigned short* ws = (unsigned short*)d_ws;
  unsigned short* xb   = ws;                // 8388608 elems (x bf16; later reused as attn out)
  unsigned short* wcat = xb + 8388608;      // 12582912 (Wq|Wk|Wv rows, [6144][2048])
  unsigned short* wob  = wcat + 12582912;   // 4194304
  unsigned short* qb   = wob + 4194304;     // 8388608  [32][2048][128]
  unsigned short* kb   = qb + 8388608;      // 8388608
  unsigned short* vtb  = kb + 8388608;      // 8388608  [32][128][2048] (transposed)

  convert_all<<<2048, 256, 0, stream>>>(x, Wq, Wk, Wv, Wo, xb, wcat, wob);
  gemm8<0><<<384, 512, 0, stream>>>(xb, wcat, 24, 6144,
                                    nullptr, nullptr, qb, kb, vtb, bq, bv);
  rope_k<<<16384, 256, 0, stream>>>((u32*)qb, (u32*)kb);
  attn_k<<<256, 512, 0, stream>>>(qb, kb, vtb, xb /* a_buf alias */);
  gemm2<1><<<256, 512, 0, stream>>>(xb, wob, 8, 2048, out, bo);
}